// Round 1
// baseline (129.319 us; speedup 1.0000x reference)
//
#include <hip/hip_runtime.h>
#include <hip/hip_bf16.h>

// Embedding lookup: out[token, :] = W[x[token], :]
//   x: int32 [4096]   (BATCH*POS = 2*2048)
//   W: fp32  [32000, 768]
//   out: fp32 [4096, 768]
//
// 768 floats per row = 192 float4. One block per token, 192 threads
// (3 waves of 64), each thread moves one float4. Row index is
// block-uniform, so all accesses are fully coalesced.

#define EMBED_DIM   768
#define VEC_PER_ROW (EMBED_DIM / 4)   // 192

__global__ __launch_bounds__(VEC_PER_ROW)
void embed_gather_kernel(const int* __restrict__ x,
                         const float4* __restrict__ W,
                         float4* __restrict__ out) {
    const int token = blockIdx.x;
    const int col   = threadIdx.x;          // 0..191
    const int row   = x[token];             // block-uniform load (scalar-cached)
    out[(size_t)token * VEC_PER_ROW + col] =
        W[(size_t)row * VEC_PER_ROW + col];
}

extern "C" void kernel_launch(void* const* d_in, const int* in_sizes, int n_in,
                              void* d_out, int out_size, void* d_ws, size_t ws_size,
                              hipStream_t stream) {
    const int*    x = (const int*)d_in[0];       // [4096] token ids
    const float4* W = (const float4*)d_in[1];    // [32000 * 192] float4
    float4*     out = (float4*)d_out;            // [4096 * 192] float4

    const int n_tokens = in_sizes[0];            // 4096
    embed_gather_kernel<<<n_tokens, VEC_PER_ROW, 0, stream>>>(x, W, out);
}